// Round 21
// baseline (16022.264 us; speedup 1.0000x reference)
//
#include <hip/hip_runtime.h>

#define HH 1024
#define TT 4096
#define NWG 256
#define NWG_PER_LAYER 128
#define JS_PER_WG 8       // 1024 / 128
#define NTHREADS 512      // 8 waves; each wave owns ONE output row j
#define LDS_BYTES 131072  // 8 waves * 4 gate rows * 1024 floats * 4 B (w_hh)

__device__ __forceinline__ float fsigmoid(float x) {
    return 1.0f / (1.0f + __expf(-x));
}
__device__ __forceinline__ float ftanh(float x) {
    float ax = fabsf(x);
    float e = __expf(-2.0f * ax);
    float t = (1.0f - e) / (1.0f + e);
    return copysignf(t, x);
}
__device__ __forceinline__ void fma4(float& a, const float4 w, const float4 v) {
    a = fmaf(w.x, v.x, a);
    a = fmaf(w.y, v.y, a);
    a = fmaf(w.z, v.z, a);
    a = fmaf(w.w, v.w, a);
}

// LLC-coherent 64B load, ONE round-trip (round-11 proven).
__device__ __forceinline__ void load64B_llc(float4 v[4], const float* p) {
    asm volatile(
        "global_load_dwordx4 %0, %4, off sc0 sc1\n\t"
        "global_load_dwordx4 %1, %4, off offset:16 sc0 sc1\n\t"
        "global_load_dwordx4 %2, %4, off offset:32 sc0 sc1\n\t"
        "global_load_dwordx4 %3, %4, off offset:48 sc0 sc1\n\t"
        "s_waitcnt vmcnt(0)"
        : "=&v"(v[0]), "=&v"(v[1]), "=&v"(v[2]), "=&v"(v[3])
        : "v"(p)
        : "memory");
}

// r13-proven thin slot barrier: lane l reads slots[4l..4l+3] with one dwordx4
// sc0 sc1 (64 lanes = all 256 slots = one LLC RT per attempt). r15/r16/r19
// law: any poll loop must stay <=16B/lane; data loads are issued once.
__device__ __forceinline__ void slot_barrier_wait(const unsigned* slots, unsigned tgt) {
    const unsigned* p = slots + 4 * (threadIdx.x & 63);
    for (;;) {
        uint4 v;
        asm volatile(
            "global_load_dwordx4 %0, %1, off sc0 sc1\n\t"
            "s_waitcnt vmcnt(0)"
            : "=&v"(v) : "v"(p) : "memory");
        const unsigned m = min(min(v.x, v.y), min(v.z, v.w));
        if (__all(m >= tgt)) break;
        __builtin_amdgcn_s_sleep(1);
    }
}

#define FOR_R(F) F(0) F(1) F(2) F(3)

// Persistent 2-layer LSTM = round-20 + 8-wave WGs (2 waves/SIMD) (r21).
// WGs [0,128): layer 0 (t = k). WGs [128,256): layer 1 (t = k-2, skew 2).
// r21 change: 512-thread WGs; each wave owns ONE j (4 gate rows). Per-CU
// work is unchanged, but 2 waves/SIMD interleave to fill ds_read/shfl
// latency gaps -- compresses the compute segment toward its ~0.1us
// throughput floor (r20's single wave/SIMD left it at ~0.9us).
// Per step: CRITICAL {1-RT h load -> w_hh GEMV (LDS) -> 4-acc butterfly ->
// +bias -> gates -> 4B h store} -> syncthreads -> ARRIVE (tid0) -> SLACK
// {gx[t+1] from 64 AGPRs/lane} -> POLL (thin, full coupling).
//   w_hh: 128 KB LDS [wave][gate r][q][lane] (conflict-free ds_read_b128)
//   w_ih: 64 AGPRs/lane (one-time v_accvgpr_write; r20-proven)
//   h1: plain ring [4][1024]; h2 recurrence reads `out` directly.
__global__ __launch_bounds__(NTHREADS, 1) void lstm2_persistent(
    const float* __restrict__ x,
    const float* __restrict__ wih0, const float* __restrict__ whh0,
    const float* __restrict__ bih0, const float* __restrict__ bhh0,
    const float* __restrict__ wih1, const float* __restrict__ whh1,
    const float* __restrict__ bih1, const float* __restrict__ bhh1,
    float* __restrict__ out,     // [T][H]  h2 (output + h2 recurrence buffer)
    float* __restrict__ ring,    // [4][H]  h1 ring (layer0 <-> layer1)
    const float* __restrict__ zbuf,   // [H] zeros (h[-1])
    unsigned* __restrict__ slots)     // 256 per-WG epoch slots (zeroed)
{
    extern __shared__ float ldsw[];   // w_hh tile, 128 KB

    const int wg   = blockIdx.x;
    const int tid  = threadIdx.x;
    const int wave = tid >> 6;        // 0..7
    const int lane = tid & 63;
    const bool isL1 = (wg >= NWG_PER_LAYER);
    const int wgl   = isL1 ? (wg - NWG_PER_LAYER) : wg;
    const int jb    = wgl * JS_PER_WG + wave;   // this wave's single output row
    const int col   = lane * 16;   // this lane's 16-elem chunk of the 1024-vector

    const float* wih = isL1 ? wih1 : wih0;
    const float* whh = isL1 ? whh1 : whh0;
    const float* bih = isL1 ? bih1 : bih0;
    const float* bhh = isL1 ? bhh1 : bhh0;

    // ---- stage w_hh into LDS: float offset = wave*4096 + r*1024 + q*256 + lane*4
    #pragma unroll
    for (int r = 0; r < 4; ++r) {
        const int row = r * HH + jb;       // gate r (i,f,g,o) of row jb
        const float4* p  = (const float4*)(whh + (size_t)row * HH + col);
        float*       wb = ldsw + wave * 4096 + r * 1024 + lane * 4;
        #pragma unroll
        for (int q = 0; q < 4; ++q)
            *(float4*)(wb + q * 256) = p[q];
    }

    // ---- w_ih into AGPRs: 4 rows x 16 floats = 64 AGPRs per lane ----
    #define DECLA(r) float AI##r##_0, AI##r##_1, AI##r##_2,  AI##r##_3, \
                           AI##r##_4, AI##r##_5, AI##r##_6,  AI##r##_7, \
                           AI##r##_8, AI##r##_9, AI##r##_10, AI##r##_11, \
                           AI##r##_12, AI##r##_13, AI##r##_14, AI##r##_15;
    FOR_R(DECLA)

    #define AW(dst, s) asm volatile("v_accvgpr_write_b32 %0, %1" : "=a"(dst) : "v"(s));
    #define AWI(r) { \
        const int row = (r) * HH + jb; \
        const float4* pw = (const float4*)(wih + (size_t)row * HH + col); \
        float4 w0 = pw[0], w1 = pw[1], w2 = pw[2], w3 = pw[3]; \
        AW(AI##r##_0,  w0.x) AW(AI##r##_1,  w0.y) AW(AI##r##_2,  w0.z) AW(AI##r##_3,  w0.w) \
        AW(AI##r##_4,  w1.x) AW(AI##r##_5,  w1.y) AW(AI##r##_6,  w1.z) AW(AI##r##_7,  w1.w) \
        AW(AI##r##_8,  w2.x) AW(AI##r##_9,  w2.y) AW(AI##r##_10, w2.z) AW(AI##r##_11, w2.w) \
        AW(AI##r##_12, w3.x) AW(AI##r##_13, w3.y) AW(AI##r##_14, w3.z) AW(AI##r##_15, w3.w) }
    FOR_R(AWI)

    // ---- bias (applied AFTER the butterfly reduce, uniform across lanes) ----
    #define DECLB(r) float B##r; { const int row = (r) * HH + jb; \
                                   B##r = bih[row] + bhh[row]; }
    FOR_R(DECLB)

    // gx per-lane partials, carried in registers across the step boundary
    #define DECLG(r) float gxp##r = 0.0f;
    FOR_R(DECLG)

    float cv = 0.0f;                     // cell state for row jb
    int loff = wave * 4096 + lane * 4;   // LDS float offset (pinned per iter)

    // AGPR input-GEMV partial (r20-proven): 1 accvgpr_read + 1 fma per term;
    // kd dummy blocks LICM hoisting the reads into spillable VGPRs.
    #define ARD(src) { asm("v_accvgpr_read_b32 %0, %1" \
                           : "=v"(tt) : "a"(src), "v"(kd)); }
    #define GXA(r) { float a = 0.0f; float tt; \
        ARD(AI##r##_0)  a = fmaf(tt, iv4[0].x, a); \
        ARD(AI##r##_1)  a = fmaf(tt, iv4[0].y, a); \
        ARD(AI##r##_2)  a = fmaf(tt, iv4[0].z, a); \
        ARD(AI##r##_3)  a = fmaf(tt, iv4[0].w, a); \
        ARD(AI##r##_4)  a = fmaf(tt, iv4[1].x, a); \
        ARD(AI##r##_5)  a = fmaf(tt, iv4[1].y, a); \
        ARD(AI##r##_6)  a = fmaf(tt, iv4[1].z, a); \
        ARD(AI##r##_7)  a = fmaf(tt, iv4[1].w, a); \
        ARD(AI##r##_8)  a = fmaf(tt, iv4[2].x, a); \
        ARD(AI##r##_9)  a = fmaf(tt, iv4[2].y, a); \
        ARD(AI##r##_10) a = fmaf(tt, iv4[2].z, a); \
        ARD(AI##r##_11) a = fmaf(tt, iv4[2].w, a); \
        ARD(AI##r##_12) a = fmaf(tt, iv4[3].x, a); \
        ARD(AI##r##_13) a = fmaf(tt, iv4[3].y, a); \
        ARD(AI##r##_14) a = fmaf(tt, iv4[3].z, a); \
        ARD(AI##r##_15) a = fmaf(tt, iv4[3].w, a); \
        gxp##r = a; }

    // ---- prologue: L0 needs gx[0] before the first step ----
    if (!isL1) {
        float4 iv4[4];
        const float4* p = (const float4*)(x + col);
        iv4[0] = p[0]; iv4[1] = p[1]; iv4[2] = p[2]; iv4[3] = p[3];
        int kd = 0;
        FOR_R(GXA)
    }

    __syncthreads();   // LDS w_hh tile ready

    for (int k = 0; k <= TT + 1; ++k) {
        // pin LDS addressing so the (address-invariant) w_hh reads can't be
        // LICM-hoisted into spillable long-lived registers
        asm volatile("" : "+v"(loff));

        const int t = isL1 ? (k - 2) : k;

        // ================= CRITICAL phase =================
        if (t >= 0 && t < TT) {
            float4 hp4[4];
            const float* hpv = (t > 0)
                ? (isL1 ? out + (size_t)(t - 1) * HH : ring + (size_t)((t - 1) & 3) * HH)
                : zbuf;
            load64B_llc(hp4, hpv + col);

            float acc0, acc1, acc2, acc3;
            #define DOTW(r) { float a = gxp##r; \
                const float4* wp = (const float4*)(ldsw + loff + (r) * 1024); \
                fma4(a, wp[0],   hp4[0]); fma4(a, wp[64],  hp4[1]); \
                fma4(a, wp[128], hp4[2]); fma4(a, wp[192], hp4[3]); \
                acc##r = a; }
            FOR_R(DOTW)

            #define REDW(m) \
                acc0 += __shfl_xor(acc0, m, 64); acc1 += __shfl_xor(acc1, m, 64); \
                acc2 += __shfl_xor(acc2, m, 64); acc3 += __shfl_xor(acc3, m, 64);
            REDW(1) REDW(2) REDW(4) REDW(8) REDW(16) REDW(32)

            // gates (PyTorch order i,f,g,o = acc0..acc3); bias post-reduce
            const float gi = fsigmoid(acc0 + B0), gf = fsigmoid(acc1 + B1);
            const float gg = ftanh(acc2 + B2),    go = fsigmoid(acc3 + B3);
            cv = gf * cv + gi * gg;
            const float h = go * ftanh(cv);

            if (lane == 0) {
                float* dstf = isL1 ? (out  + (size_t)t * HH + jb)
                                   : (ring + (size_t)(t & 3) * HH + jb);
                __hip_atomic_store((unsigned*)dstf, __float_as_uint(h),
                                   __ATOMIC_RELAXED, __HIP_MEMORY_SCOPE_AGENT);
            }
        }

        __syncthreads();   // all 8 waves drain their h stores (vmcnt before s_barrier)

        if (k <= TT) {
            // ================= ARRIVE: plain per-WG epoch store ==============
            if (tid == 0) {
                asm volatile("s_waitcnt vmcnt(0)" ::: "memory");
                __hip_atomic_store(&slots[wg], (unsigned)(k + 1),
                                   __ATOMIC_RELAXED, __HIP_MEMORY_SCOPE_AGENT);
            }

            // ====== SLACK: gx for next timestep (AGPR w_ih, no L2 stream) ====
            {
                const int tn = t + 1;
                if (tn >= 0 && tn < TT) {
                    float4 iv4[4];
                    if (!isL1) {
                        const float4* p = (const float4*)(x + (size_t)tn * HH + col);
                        iv4[0] = p[0]; iv4[1] = p[1]; iv4[2] = p[2]; iv4[3] = p[3];
                    } else {
                        // h1[tn]: published by L0 at step tn, covered by the
                        // previous barrier
                        load64B_llc(iv4, ring + (size_t)(tn & 3) * HH + col);
                    }
                    int kd = k;
                    FOR_R(GXA)
                }
            }
            // anchor gx results so the slack work cannot sink past the poll
            asm volatile("" : "+v"(gxp0), "+v"(gxp1), "+v"(gxp2), "+v"(gxp3));

            // ================= POLL: all 256 slots >= k+1 (thin) =============
            slot_barrier_wait(slots, (unsigned)(k + 1));
        }
    }
}

extern "C" void kernel_launch(void* const* d_in, const int* in_sizes, int n_in,
                              void* d_out, int out_size, void* d_ws, size_t ws_size,
                              hipStream_t stream) {
    (void)in_sizes; (void)n_in; (void)out_size; (void)ws_size;
    const float* x    = (const float*)d_in[0];
    const float* wih0 = (const float*)d_in[1];
    const float* whh0 = (const float*)d_in[2];
    const float* bih0 = (const float*)d_in[3];
    const float* bhh0 = (const float*)d_in[4];
    const float* wih1 = (const float*)d_in[5];
    const float* whh1 = (const float*)d_in[6];
    const float* bih1 = (const float*)d_in[7];
    const float* bhh1 = (const float*)d_in[8];
    float* out = (float*)d_out;

    // ws layout: [0,1024) slots (256 x 4B) | [4096,8192) zbuf |
    //            [8192,24576) ring (4 slots x 4 KB)
    unsigned* slots = (unsigned*)d_ws;
    float*    zbuf  = (float*)((char*)d_ws + 4096);
    float*    ring  = (float*)((char*)d_ws + 8192);

    // allow 128 KB dynamic LDS (160 KB available per CU on gfx950)
    (void)hipFuncSetAttribute((const void*)lstm2_persistent,
                              hipFuncAttributeMaxDynamicSharedMemorySize, LDS_BYTES);

    // zero slots + zbuf + ring every call (stream-ordered, graph-capturable)
    (void)hipMemsetAsync(d_ws, 0, 24576, stream);

    hipLaunchKernelGGL(lstm2_persistent, dim3(NWG), dim3(NTHREADS), LDS_BYTES, stream,
                       x, wih0, whh0, bih0, bhh0,
                       wih1, whh1, bih1, bhh1, out, ring, zbuf, slots);
}

// Round 22
// 15421.892 us; speedup vs baseline: 1.0389x; 1.0389x over previous
//
#include <hip/hip_runtime.h>

#define HH 1024
#define TT 4096
#define NWG 256
#define NWG_PER_LAYER 128
#define JS_PER_WG 8     // 1024 / 128
#define JS_PER_WAVE 2   // 8 j's / 4 waves
#define LDS_BYTES 131072  // 4 waves * 8 rows * 1024 floats * 4 B (w_hh tile)

__device__ __forceinline__ float fsigmoid(float x) {
    return 1.0f / (1.0f + __expf(-x));
}
__device__ __forceinline__ float ftanh(float x) {
    float ax = fabsf(x);
    float e = __expf(-2.0f * ax);
    float t = (1.0f - e) / (1.0f + e);
    return copysignf(t, x);
}
__device__ __forceinline__ void fma4(float& a, const float4 w, const float4 v) {
    a = fmaf(w.x, v.x, a);
    a = fmaf(w.y, v.y, a);
    a = fmaf(w.z, v.z, a);
    a = fmaf(w.w, v.w, a);
}

// LLC-coherent 64B load, ONE round-trip (round-11 proven).
__device__ __forceinline__ void load64B_llc(float4 v[4], const float* p) {
    asm volatile(
        "global_load_dwordx4 %0, %4, off sc0 sc1\n\t"
        "global_load_dwordx4 %1, %4, off offset:16 sc0 sc1\n\t"
        "global_load_dwordx4 %2, %4, off offset:32 sc0 sc1\n\t"
        "global_load_dwordx4 %3, %4, off offset:48 sc0 sc1\n\t"
        "s_waitcnt vmcnt(0)"
        : "=&v"(v[0]), "=&v"(v[1]), "=&v"(v[2]), "=&v"(v[3])
        : "v"(p)
        : "memory");
}

// r13-proven thin slot barrier: lane l reads slots[4l..4l+3] with one dwordx4
// sc0 sc1 (64 lanes = all 256 slots = one LLC RT per attempt). r15/r16/r19
// law: any poll loop must stay <=16B/lane; data loads are issued once.
__device__ __forceinline__ void slot_barrier_wait(const unsigned* slots, unsigned tgt) {
    const unsigned* p = slots + 4 * (threadIdx.x & 63);
    for (;;) {
        uint4 v;
        asm volatile(
            "global_load_dwordx4 %0, %1, off sc0 sc1\n\t"
            "s_waitcnt vmcnt(0)"
            : "=&v"(v) : "v"(p) : "memory");
        const unsigned m = min(min(v.x, v.y), min(v.z, v.w));
        if (__all(m >= tgt)) break;
        __builtin_amdgcn_s_sleep(1);
    }
}

#define FOR_R(F) F(0) F(1) F(2) F(3) F(4) F(5) F(6) F(7)

// Persistent 2-layer LSTM = round-13 skeleton + AGPR-resident w_ih (r20; BEST:
// 15.53 ms = 3.79 us/step; r21's 8-wave variant was neutral -> reverted).
// WGs [0,128): layer 0 (t = k). WGs [128,256): layer 1 (t = k-2, skew 2).
// Per step: CRITICAL {1-RT h load -> w_hh GEMV (LDS) -> reduce -> +bias ->
// gates -> store h} -> syncthreads -> ARRIVE (tid0: slot[wg]=k+1) -> SLACK
// {gx[t+1] = w_ih @ iv from 128 AGPRs/lane: pure register work, no L2
// stream (r20 win: FETCH 2.45GB -> 250MB, -3.4ms)} -> POLL (thin, full
// coupling).
//   w_hh: 128 KB LDS [wave][row][q][lane] (conflict-free ds_read_b128)
//   w_ih: 128 AGPRs/lane (one-time v_accvgpr_write; unified RF 512/wave)
//   h1: plain ring [4][1024]; h2 recurrence reads `out` directly.
__global__ __launch_bounds__(256, 1) void lstm2_persistent(
    const float* __restrict__ x,
    const float* __restrict__ wih0, const float* __restrict__ whh0,
    const float* __restrict__ bih0, const float* __restrict__ bhh0,
    const float* __restrict__ wih1, const float* __restrict__ whh1,
    const float* __restrict__ bih1, const float* __restrict__ bhh1,
    float* __restrict__ out,     // [T][H]  h2 (output + h2 recurrence buffer)
    float* __restrict__ ring,    // [4][H]  h1 ring (layer0 <-> layer1)
    const float* __restrict__ zbuf,   // [H] zeros (h[-1])
    unsigned* __restrict__ slots)     // 256 per-WG epoch slots (zeroed)
{
    extern __shared__ float ldsw[];   // w_hh tile, 128 KB

    const int wg   = blockIdx.x;
    const int tid  = threadIdx.x;
    const int wave = tid >> 6;
    const int lane = tid & 63;
    const bool isL1 = (wg >= NWG_PER_LAYER);
    const int wgl   = isL1 ? (wg - NWG_PER_LAYER) : wg;
    const int jbase = wgl * JS_PER_WG + wave * JS_PER_WAVE;
    const int col   = lane * 16;   // this lane's 16-elem chunk of the 1024-vector

    const float* wih = isL1 ? wih1 : wih0;
    const float* whh = isL1 ? whh1 : whh0;
    const float* bih = isL1 ? bih1 : bih0;
    const float* bhh = isL1 ? bhh1 : bhh0;

    // ---- stage w_hh into LDS: float offset = wave*8192 + r*1024 + q*256 + lane*4
    #pragma unroll
    for (int r = 0; r < 8; ++r) {
        const int row = (r & 3) * HH + (jbase + (r >> 2));
        const float4* p  = (const float4*)(whh + (size_t)row * HH + col);
        float*       wb = ldsw + wave * 8192 + r * 1024 + lane * 4;
        #pragma unroll
        for (int q = 0; q < 4; ++q)
            *(float4*)(wb + q * 256) = p[q];
    }

    // ---- w_ih into AGPRs: 8 rows x 16 floats = 128 AGPRs per lane ----
    #define DECLA(r) float AI##r##_0, AI##r##_1, AI##r##_2,  AI##r##_3, \
                           AI##r##_4, AI##r##_5, AI##r##_6,  AI##r##_7, \
                           AI##r##_8, AI##r##_9, AI##r##_10, AI##r##_11, \
                           AI##r##_12, AI##r##_13, AI##r##_14, AI##r##_15;
    FOR_R(DECLA)

    #define AW(dst, s) asm volatile("v_accvgpr_write_b32 %0, %1" : "=a"(dst) : "v"(s));
    #define AWI(r) { \
        const int row = ((r) & 3) * HH + (jbase + ((r) >> 2)); \
        const float4* pw = (const float4*)(wih + (size_t)row * HH + col); \
        float4 w0 = pw[0], w1 = pw[1], w2 = pw[2], w3 = pw[3]; \
        AW(AI##r##_0,  w0.x) AW(AI##r##_1,  w0.y) AW(AI##r##_2,  w0.z) AW(AI##r##_3,  w0.w) \
        AW(AI##r##_4,  w1.x) AW(AI##r##_5,  w1.y) AW(AI##r##_6,  w1.z) AW(AI##r##_7,  w1.w) \
        AW(AI##r##_8,  w2.x) AW(AI##r##_9,  w2.y) AW(AI##r##_10, w2.z) AW(AI##r##_11, w2.w) \
        AW(AI##r##_12, w3.x) AW(AI##r##_13, w3.y) AW(AI##r##_14, w3.z) AW(AI##r##_15, w3.w) }
    FOR_R(AWI)

    // ---- bias (applied AFTER the butterfly reduce, uniform across lanes) ----
    #define DECLB(r) float B##r; { const int row = ((r)&3)*HH + (jbase + ((r)>>2)); \
                                   B##r = bih[row] + bhh[row]; }
    FOR_R(DECLB)

    // gx per-lane partials, carried in registers across the step boundary
    #define DECLG(r) float gxp##r = 0.0f;
    FOR_R(DECLG)

    float c0v = 0.0f, c1v = 0.0f;
    int loff = wave * 8192 + lane * 4;   // LDS float offset (pinned per iter)

    // AGPR input-GEMV partial: gxp_r = w_ih[rows(r)][col..col+16) @ iv4.
    // Each term: 1 v_accvgpr_read (kd dummy blocks LICM hoisting all 128
    // reads into spillable VGPRs) + 1 fmaf. Pure register work, no memory.
    #define ARD(src) { asm("v_accvgpr_read_b32 %0, %1" \
                           : "=v"(tt) : "a"(src), "v"(kd)); }
    #define GXA(r) { float a = 0.0f; float tt; \
        ARD(AI##r##_0)  a = fmaf(tt, iv4[0].x, a); \
        ARD(AI##r##_1)  a = fmaf(tt, iv4[0].y, a); \
        ARD(AI##r##_2)  a = fmaf(tt, iv4[0].z, a); \
        ARD(AI##r##_3)  a = fmaf(tt, iv4[0].w, a); \
        ARD(AI##r##_4)  a = fmaf(tt, iv4[1].x, a); \
        ARD(AI##r##_5)  a = fmaf(tt, iv4[1].y, a); \
        ARD(AI##r##_6)  a = fmaf(tt, iv4[1].z, a); \
        ARD(AI##r##_7)  a = fmaf(tt, iv4[1].w, a); \
        ARD(AI##r##_8)  a = fmaf(tt, iv4[2].x, a); \
        ARD(AI##r##_9)  a = fmaf(tt, iv4[2].y, a); \
        ARD(AI##r##_10) a = fmaf(tt, iv4[2].z, a); \
        ARD(AI##r##_11) a = fmaf(tt, iv4[2].w, a); \
        ARD(AI##r##_12) a = fmaf(tt, iv4[3].x, a); \
        ARD(AI##r##_13) a = fmaf(tt, iv4[3].y, a); \
        ARD(AI##r##_14) a = fmaf(tt, iv4[3].z, a); \
        ARD(AI##r##_15) a = fmaf(tt, iv4[3].w, a); \
        gxp##r = a; }

    // ---- prologue: L0 needs gx[0] before the first step ----
    if (!isL1) {
        float4 iv4[4];
        const float4* p = (const float4*)(x + col);
        iv4[0] = p[0]; iv4[1] = p[1]; iv4[2] = p[2]; iv4[3] = p[3];
        int kd = 0;
        FOR_R(GXA)
    }

    __syncthreads();   // LDS w_hh tile ready

    for (int k = 0; k <= TT + 1; ++k) {
        // pin LDS addressing so the (address-invariant) w_hh reads can't be
        // LICM-hoisted into spillable long-lived registers
        asm volatile("" : "+v"(loff));

        const int t = isL1 ? (k - 2) : k;

        // ================= CRITICAL phase (byte-identical to r13) ===========
        if (t >= 0 && t < TT) {
            float4 hp4[4];
            const float* hpv = (t > 0)
                ? (isL1 ? out + (size_t)(t - 1) * HH : ring + (size_t)((t - 1) & 3) * HH)
                : zbuf;
            load64B_llc(hp4, hpv + col);

            float acc0, acc1, acc2, acc3, acc4, acc5, acc6, acc7;
            #define DOTW(r) { float a = gxp##r; \
                const float4* wp = (const float4*)(ldsw + loff + (r) * 1024); \
                fma4(a, wp[0],   hp4[0]); fma4(a, wp[64],  hp4[1]); \
                fma4(a, wp[128], hp4[2]); fma4(a, wp[192], hp4[3]); \
                acc##r = a; }
            FOR_R(DOTW)

            #define REDW(m) \
                acc0 += __shfl_xor(acc0, m, 64); acc1 += __shfl_xor(acc1, m, 64); \
                acc2 += __shfl_xor(acc2, m, 64); acc3 += __shfl_xor(acc3, m, 64); \
                acc4 += __shfl_xor(acc4, m, 64); acc5 += __shfl_xor(acc5, m, 64); \
                acc6 += __shfl_xor(acc6, m, 64); acc7 += __shfl_xor(acc7, m, 64);
            REDW(1) REDW(2) REDW(4) REDW(8) REDW(16) REDW(32)

            // gates (PyTorch order i,f,g,o); bias added post-reduce
            const float gi0 = fsigmoid(acc0 + B0), gf0 = fsigmoid(acc1 + B1);
            const float gg0 = ftanh(acc2 + B2),    go0 = fsigmoid(acc3 + B3);
            c0v = gf0 * c0v + gi0 * gg0;
            const float h0 = go0 * ftanh(c0v);
            const float gi1 = fsigmoid(acc4 + B4), gf1 = fsigmoid(acc5 + B5);
            const float gg1 = ftanh(acc6 + B6),    go1 = fsigmoid(acc7 + B7);
            c1v = gf1 * c1v + gi1 * gg1;
            const float h1v = go1 * ftanh(c1v);

            if (lane == 0) {
                float2 hv = make_float2(h0, h1v);   // jbase, jbase+1 (jbase even)
                unsigned long long bits;
                __builtin_memcpy(&bits, &hv, 8);
                float* dstf = isL1 ? (out  + (size_t)t * HH + jbase)
                                   : (ring + (size_t)(t & 3) * HH + jbase);
                __hip_atomic_store((unsigned long long*)dstf, bits,
                                   __ATOMIC_RELAXED, __HIP_MEMORY_SCOPE_AGENT);
            }
        }

        __syncthreads();   // all 4 waves drain their h stores (vmcnt before s_barrier)

        if (k <= TT) {
            // ================= ARRIVE: plain per-WG epoch store ==============
            if (tid == 0) {
                asm volatile("s_waitcnt vmcnt(0)" ::: "memory");
                __hip_atomic_store(&slots[wg], (unsigned)(k + 1),
                                   __ATOMIC_RELAXED, __HIP_MEMORY_SCOPE_AGENT);
            }

            // ====== SLACK: gx for next timestep (AGPR w_ih, no L2 stream) ====
            {
                const int tn = t + 1;
                if (tn >= 0 && tn < TT) {
                    float4 iv4[4];
                    if (!isL1) {
                        const float4* p = (const float4*)(x + (size_t)tn * HH + col);
                        iv4[0] = p[0]; iv4[1] = p[1]; iv4[2] = p[2]; iv4[3] = p[3];
                    } else {
                        // h1[tn]: published by L0 at step tn, covered by the
                        // previous barrier
                        load64B_llc(iv4, ring + (size_t)(tn & 3) * HH + col);
                    }
                    int kd = k;
                    FOR_R(GXA)
                }
            }
            // anchor gx results so the slack work cannot sink past the poll
            asm volatile("" : "+v"(gxp0), "+v"(gxp1), "+v"(gxp2), "+v"(gxp3),
                             "+v"(gxp4), "+v"(gxp5), "+v"(gxp6), "+v"(gxp7));

            // ================= POLL: all 256 slots >= k+1 (thin) =============
            slot_barrier_wait(slots, (unsigned)(k + 1));
        }
    }
}

extern "C" void kernel_launch(void* const* d_in, const int* in_sizes, int n_in,
                              void* d_out, int out_size, void* d_ws, size_t ws_size,
                              hipStream_t stream) {
    (void)in_sizes; (void)n_in; (void)out_size; (void)ws_size;
    const float* x    = (const float*)d_in[0];
    const float* wih0 = (const float*)d_in[1];
    const float* whh0 = (const float*)d_in[2];
    const float* bih0 = (const float*)d_in[3];
    const float* bhh0 = (const float*)d_in[4];
    const float* wih1 = (const float*)d_in[5];
    const float* whh1 = (const float*)d_in[6];
    const float* bih1 = (const float*)d_in[7];
    const float* bhh1 = (const float*)d_in[8];
    float* out = (float*)d_out;

    // ws layout: [0,1024) slots (256 x 4B) | [4096,8192) zbuf |
    //            [8192,24576) ring (4 slots x 4 KB)
    unsigned* slots = (unsigned*)d_ws;
    float*    zbuf  = (float*)((char*)d_ws + 4096);
    float*    ring  = (float*)((char*)d_ws + 8192);

    // allow 128 KB dynamic LDS (160 KB available per CU on gfx950)
    (void)hipFuncSetAttribute((const void*)lstm2_persistent,
                              hipFuncAttributeMaxDynamicSharedMemorySize, LDS_BYTES);

    // zero slots + zbuf + ring every call (stream-ordered, graph-capturable)
    (void)hipMemsetAsync(d_ws, 0, 24576, stream);

    hipLaunchKernelGGL(lstm2_persistent, dim3(NWG), dim3(256), LDS_BYTES, stream,
                       x, wih0, whh0, bih0, bhh0,
                       wih1, whh1, bih1, bhh1, out, ring, zbuf, slots);
}